// Round 2
// baseline (809.302 us; speedup 1.0000x reference)
//
#include <hip/hip_runtime.h>
#include <cstdint>
#include <cstddef>

// B=2, T=2048, HID=2048, H=16, D=128; recent window m=512, ws=1536, evict=1535.

#define DEVINL __device__ __forceinline__

typedef float  f32x4  __attribute__((ext_vector_type(4)));
typedef __bf16 bf16x8 __attribute__((ext_vector_type(8)));

DEVINL float bf2f(unsigned short u){
  unsigned int x = ((unsigned int)u) << 16;
  return __builtin_bit_cast(float, x);
}
DEVINL unsigned short f2bf(float f){
  unsigned int u = __builtin_bit_cast(unsigned int, f);
  u = (u + 0x7fffu + ((u >> 16) & 1u)) >> 16;   // RNE
  return (unsigned short)u;
}

DEVINL void load_lds16(const void* g, void* l){
  __builtin_amdgcn_global_load_lds(
      (const __attribute__((address_space(1))) void*)g,
      (__attribute__((address_space(3))) void*)l, 16, 0, 0);
}

// Q pre-scale: log2(e)/sqrt(128) folded into RoPE'd Q so flash softmax is pure exp2.
#define QSCALE 0.127517432f

// ---------------------------------------------------------------- convert (all 5 tensors, one launch)
__global__ void cvt_all_kernel(const float* __restrict__ hs, const float* __restrict__ qw,
                               const float* __restrict__ kw, const float* __restrict__ vw,
                               const float* __restrict__ ow,
                               unsigned short* __restrict__ hsb, unsigned short* __restrict__ qwb,
                               unsigned short* __restrict__ kwb, unsigned short* __restrict__ vwb,
                               unsigned short* __restrict__ owb){
  int i = blockIdx.x * 256 + threadIdx.x;     // 6291456 float4 groups total
  const float* s; unsigned short* d; int off;
  if (i < 2097152){ s = hs; d = hsb; off = i; }
  else {
    int j = i - 2097152; int w = j >> 20; off = j & 1048575;
    s = (w == 0) ? qw : (w == 1) ? kw : (w == 2) ? vw : ow;
    d = (w == 0) ? qwb : (w == 1) ? kwb : (w == 2) ? vwb : owb;
  }
  float4 v = reinterpret_cast<const float4*>(s)[off];
  uint2 o;
  o.x = (unsigned)f2bf(v.x) | ((unsigned)f2bf(v.y) << 16);
  o.y = (unsigned)f2bf(v.z) | ((unsigned)f2bf(v.w) << 16);
  reinterpret_cast<uint2*>(d)[off] = o;
}

// ---------------------------------------------------------------- GEMM C = A @ B^T
// MODE 0: bf16 store scattered to (B,H,T,D)   [Q,K proj]
// MODE 1: bf16 store scattered to (B,H,D,T)   [V proj, pre-transposed]
// MODE 2: fp32 store row-major (M,N)          [output proj]
template<int MODE>
__global__ __launch_bounds__(256, 2)
void gemm_bt_kernel(const unsigned short* __restrict__ A,
                    const unsigned short* __restrict__ B,
                    void* __restrict__ out, int M, int N, int K){
  __shared__ unsigned short As[128 * 64];
  __shared__ unsigned short Bs[128 * 64];
  const int tid = threadIdx.x, wave = tid >> 6, lane = tid & 63;
  const int m16 = lane & 15, quad = lane >> 4;
  const int m0 = blockIdx.y * 128, n0 = blockIdx.x * 128;
  const int wm = wave >> 1, wn = wave & 1;

  f32x4 acc[4][4] = {};

  for (int k0 = 0; k0 < K; k0 += 64){
    __syncthreads();
    #pragma unroll
    for (int i = 0; i < 4; ++i){
      int r  = wave * 32 + i * 8 + (lane >> 3);
      int c8 = (lane & 7) ^ (r & 7);
      load_lds16(A + (size_t)(m0 + r) * K + k0 + c8 * 8, &As[(wave * 32 + i * 8) * 64]);
      load_lds16(B + (size_t)(n0 + r) * K + k0 + c8 * 8, &Bs[(wave * 32 + i * 8) * 64]);
    }
    __syncthreads();
    #pragma unroll
    for (int kc = 0; kc < 2; ++kc){
      bf16x8 af[4], bfr[4];
      #pragma unroll
      for (int mt = 0; mt < 4; ++mt){
        int r = wm * 64 + mt * 16 + m16;
        af[mt] = *reinterpret_cast<const bf16x8*>(&As[(r * 8 + ((quad + 4 * kc) ^ (r & 7))) * 8]);
      }
      #pragma unroll
      for (int nt = 0; nt < 4; ++nt){
        int r = wn * 64 + nt * 16 + m16;
        bfr[nt] = *reinterpret_cast<const bf16x8*>(&Bs[(r * 8 + ((quad + 4 * kc) ^ (r & 7))) * 8]);
      }
      #pragma unroll
      for (int mt = 0; mt < 4; ++mt)
        #pragma unroll
        for (int nt = 0; nt < 4; ++nt)
          acc[mt][nt] = __builtin_amdgcn_mfma_f32_16x16x32_bf16(af[mt], bfr[nt], acc[mt][nt], 0, 0, 0);
    }
  }

  #pragma unroll
  for (int mt = 0; mt < 4; ++mt){
    #pragma unroll
    for (int nt = 0; nt < 4; ++nt){
      #pragma unroll
      for (int reg = 0; reg < 4; ++reg){
        int m = m0 + wm * 64 + mt * 16 + quad * 4 + reg;
        int n = n0 + wn * 64 + nt * 16 + m16;
        float v = acc[mt][nt][reg];
        if constexpr (MODE == 0){
          ((unsigned short*)out)[((((size_t)(m >> 11)) * 16 + (n >> 7)) * 2048 + (m & 2047)) * 128 + (n & 127)] = f2bf(v);
        } else if constexpr (MODE == 1){
          ((unsigned short*)out)[((((size_t)(m >> 11)) * 16 + (n >> 7)) * 128 + (n & 127)) * 2048 + (m & 2047)] = f2bf(v);
        } else {
          ((float*)out)[(size_t)m * N + n] = v;
        }
      }
    }
  }
}

// ---------------------------------------------------------------- RoPE (in-place, Q then K; Q gets QSCALE)
__global__ void rope_kernel(unsigned short* __restrict__ Q, unsigned short* __restrict__ K){
  int gid = blockIdx.x * 256 + threadIdx.x;     // 2^23 threads
  int d2 = gid & 63;
  int t  = (gid >> 6) & 2047;
  int bh = (gid >> 17) & 31;
  int isK = gid >> 22;
  unsigned short* P = isK ? K : Q;
  float sc = isK ? 1.0f : QSCALE;
  size_t base = ((size_t)bh * 2048 + t) * 128;
  float x1 = bf2f(P[base + d2]);
  float x2 = bf2f(P[base + d2 + 64]);
  float inv = expf(-(float)d2 * 0.14391156606007266f);  // ln(10000)/64
  float fr = (float)t * inv;
  float sn, cs;
  sincosf(fr, &sn, &cs);
  P[base + d2]      = f2bf((x1 * cs - x2 * sn) * sc);
  P[base + d2 + 64] = f2bf((x2 * cs + x1 * sn) * sc);
}

// ---------------------------------------------------------------- CAM mask
DEVINL unsigned int rotl32(unsigned int x, int r){ return (x << r) | (x >> (32 - r)); }

__device__ float threefry_u01(int i){
  unsigned int c0 = (i < 16) ? (unsigned)i : (unsigned)(i - 16);
  unsigned int c1 = (i < 16) ? (unsigned)(i + 16) : (unsigned)i;
  bool hi = (i >= 16);
  unsigned int k0 = 0u, k1 = 42u, k2 = 0x1BD11BDAu ^ k0 ^ k1;
  unsigned int ks[3] = {k0, k1, k2};
  unsigned int x0 = c0 + k0, x1 = c1 + k1;
  const int R0[4] = {13, 15, 26, 6}, R1[4] = {17, 29, 16, 24};
  #pragma unroll
  for (int r = 0; r < 5; ++r){
    const int* RR = (r & 1) ? R1 : R0;
    #pragma unroll
    for (int j = 0; j < 4; ++j){ x0 += x1; x1 = rotl32(x1, RR[j]); x1 ^= x0; }
    x0 += ks[(r + 1) % 3];
    x1 += ks[(r + 2) % 3] + (unsigned)(r + 1);
  }
  unsigned int bits = hi ? x1 : x0;
  return __builtin_bit_cast(float, (bits >> 9) | 0x3f800000u) - 1.0f;
}

DEVINL float wred_max(float v){
  #pragma unroll
  for (int m = 1; m < 64; m <<= 1) v = fmaxf(v, __shfl_xor(v, m));
  return v;
}
DEVINL float wred_sum(float v){
  #pragma unroll
  for (int m = 1; m < 64; m <<= 1) v += __shfl_xor(v, m);
  return v;
}

__global__ __launch_bounds__(256)
void cam_kernel(const unsigned short* __restrict__ Q,
                const unsigned short* __restrict__ K,
                unsigned short* __restrict__ Vt){
  const int bh = blockIdx.x, tid = threadIdx.x;
  __shared__ float qv[128];
  __shared__ float redm[4], reds[4], redw[4];
  __shared__ float e1535s;
  __shared__ float bc0;
  if (tid < 128) qv[tid] = bf2f(Q[((size_t)bh * 2048 + 2047) * 128 + tid]);
  __syncthreads();

  float sc[8];
  float smax = -1e30f;
  #pragma unroll
  for (int j = 0; j < 8; ++j){
    int k = tid + j * 256;
    const uint4* kr4 = reinterpret_cast<const uint4*>(K + ((size_t)bh * 2048 + k) * 128);
    float acc = 0.f;
    #pragma unroll
    for (int c = 0; c < 16; ++c){
      uint4 pk = kr4[c];
      acc += qv[c * 8 + 0] * bf2f((unsigned short)(pk.x & 0xffff));
      acc += qv[c * 8 + 1] * bf2f((unsigned short)(pk.x >> 16));
      acc += qv[c * 8 + 2] * bf2f((unsigned short)(pk.y & 0xffff));
      acc += qv[c * 8 + 3] * bf2f((unsigned short)(pk.y >> 16));
      acc += qv[c * 8 + 4] * bf2f((unsigned short)(pk.z & 0xffff));
      acc += qv[c * 8 + 5] * bf2f((unsigned short)(pk.z >> 16));
      acc += qv[c * 8 + 6] * bf2f((unsigned short)(pk.w & 0xffff));
      acc += qv[c * 8 + 7] * bf2f((unsigned short)(pk.w >> 16));
    }
    sc[j] = acc;                                 // Q already carries scale*log2e
    smax = fmaxf(smax, sc[j]);
  }
  int wave = tid >> 6, lane = tid & 63;
  float wm = wred_max(smax);
  if (lane == 0) redm[wave] = wm;
  __syncthreads();
  float M = fmaxf(fmaxf(redm[0], redm[1]), fmaxf(redm[2], redm[3]));
  float tsum = 0.f, wsum = 0.f;
  #pragma unroll
  for (int j = 0; j < 8; ++j){
    int k = tid + j * 256;
    float e = exp2f(sc[j] - M);                  // 2^(s*log2e) == e^s
    if (k == 1535) e1535s = e;
    tsum += e;
    if (k >= 1536) wsum += e;
  }
  tsum = wred_sum(tsum); wsum = wred_sum(wsum);
  if (lane == 0){ reds[wave] = tsum; redw[wave] = wsum; }
  __syncthreads();
  if (tid == 0){
    float sum = reds[0] + reds[1] + reds[2] + reds[3];
    float wsm = redw[0] + redw[1] + redw[2] + redw[3];
    float abar = e1535s / sum;
    float avg  = fmaxf(wsm / (512.f * sum), 1e-6f);
    float pr   = abar / avg;
    pr = fminf(fmaxf(pr, 0.f), 1.f);
    float u = threefry_u01(bh);
    bc0 = (u < pr) ? (1.f / 512.f) : 0.f;
  }
  __syncthreads();
  float ves = bc0;
  if (ves != 0.f){
    for (int idx = tid; idx < 128 * 64; idx += 256){
      int d = idx >> 6, c = idx & 63;
      unsigned short* row = Vt + ((size_t)bh * 128 + d) * 2048;
      float ve = bf2f(row[1535]) * ves;
      uint4* p = reinterpret_cast<uint4*>(row + 1536) + c;
      uint4 pk = *p;
      unsigned short h0 = f2bf(bf2f((unsigned short)(pk.x & 0xffff)) + ve);
      unsigned short h1 = f2bf(bf2f((unsigned short)(pk.x >> 16)) + ve);
      unsigned short h2 = f2bf(bf2f((unsigned short)(pk.y & 0xffff)) + ve);
      unsigned short h3 = f2bf(bf2f((unsigned short)(pk.y >> 16)) + ve);
      unsigned short h4 = f2bf(bf2f((unsigned short)(pk.z & 0xffff)) + ve);
      unsigned short h5 = f2bf(bf2f((unsigned short)(pk.z >> 16)) + ve);
      unsigned short h6 = f2bf(bf2f((unsigned short)(pk.w & 0xffff)) + ve);
      unsigned short h7 = f2bf(bf2f((unsigned short)(pk.w >> 16)) + ve);
      pk.x = (unsigned)h0 | ((unsigned)h1 << 16);
      pk.y = (unsigned)h2 | ((unsigned)h3 << 16);
      pk.z = (unsigned)h4 | ((unsigned)h5 << 16);
      pk.w = (unsigned)h6 | ((unsigned)h7 << 16);
      *p = pk;
    }
  }
}

// ---------------------------------------------------------------- flash attention v2
// Work-balanced pairing: block g handles 64-row q-tiles {g, 31-g}; shared K-loop of 32-g tiles.
// Double-buffered K/V LDS; P overlays the (dead-after-preload) Q staging buffer.
__global__ __launch_bounds__(256, 2)
void flash_kernel(const unsigned short* __restrict__ Q,
                  const unsigned short* __restrict__ K,
                  const unsigned short* __restrict__ Vt,
                  unsigned short* __restrict__ AO){
  __shared__ unsigned short Qs[64 * 128];       // 16KB; becomes per-wave P after preload
  __shared__ unsigned short Ks0[64 * 128];      // 16KB
  __shared__ unsigned short Vs0[128 * 64];      // 16KB
  __shared__ unsigned short Ks1[64 * 128];      // 16KB
  __shared__ unsigned short Vs1[128 * 64];      // 16KB  -> 80KB total, 2 blocks/CU
  const int g = blockIdx.x, bh = blockIdx.y;
  const int tid = threadIdx.x, wave = tid >> 6, lane = tid & 63;
  const int m16 = lane & 15, quad = lane >> 4;
  const int qt1 = g, qt2 = 31 - g;              // 64-row q-tile ids
  const int nkt = 32 - g;                       // shared K-tile count (q1 range subset of q2's)
  unsigned short* Pw = Qs + wave * 2048;        // per-wave 16x64 P, inside wave's own Q span

  auto stageQ = [&](int qt){
    size_t qb = ((size_t)bh * 2048 + (size_t)qt * 64) * 128;
    #pragma unroll
    for (int i = 0; i < 4; ++i){
      int r   = wave * 16 + i * 4 + (lane >> 4);
      int c16 = (lane & 15) ^ (r & 15);
      load_lds16(Q + qb + (size_t)r * 128 + c16 * 8, &Qs[(wave * 16 + i * 4) * 128]);
    }
  };
  auto readQf = [&](bf16x8 (&qf)[4]){
    int r = wave * 16 + m16;
    #pragma unroll
    for (int kc = 0; kc < 4; ++kc)
      qf[kc] = *reinterpret_cast<const bf16x8*>(&Qs[(r * 16 + ((quad + 4 * kc) ^ (r & 15))) * 8]);
  };
  auto stageKV = [&](int kt, unsigned short* Ks, unsigned short* Vs){
    size_t kb = ((size_t)bh * 2048 + (size_t)kt * 64) * 128;
    #pragma unroll
    for (int i = 0; i < 4; ++i){
      int r   = wave * 16 + i * 4 + (lane >> 4);
      int c16 = (lane & 15) ^ (r & 15);
      load_lds16(K + kb + (size_t)r * 128 + c16 * 8, &Ks[(wave * 16 + i * 4) * 128]);
    }
    size_t vb = (size_t)bh * 128 * 2048 + (size_t)kt * 64;
    #pragma unroll
    for (int i = 0; i < 4; ++i){
      int r  = wave * 32 + i * 8 + (lane >> 3);
      int c8 = (lane & 7) ^ (r & 7);
      load_lds16(Vt + vb + (size_t)r * 2048 + c8 * 8, &Vs[(wave * 32 + i * 8) * 64]);
    }
  };

  bf16x8 qf1[4], qf2[4];
  stageQ(qt1);
  __syncthreads();
  readQf(qf1);
  __syncthreads();
  stageQ(qt2);
  __syncthreads();
  readQf(qf2);

  f32x4 o1[8] = {}, o2[8] = {};
  f32x4 m1, m2, l1 = {}, l2 = {};
  { f32x4 v = {-1e30f, -1e30f, -1e30f, -1e30f}; m1 = v; m2 = v; }

  auto process = [&](bf16x8 (&qf)[4], f32x4& mst, f32x4& lst, f32x4 (&oacc)[8],
                     const unsigned short* Ks, const unsigned short* Vs, bool diag){
    f32x4 s[4] = {};
    #pragma unroll
    for (int kc = 0; kc < 4; ++kc){
      #pragma unroll
      for (int nt = 0; nt < 4; ++nt){
        int r = nt * 16 + m16;
        bf16x8 kf = *reinterpret_cast<const bf16x8*>(&Ks[(r * 16 + ((quad + 4 * kc) ^ (r & 15))) * 8]);
        s[nt] = __builtin_amdgcn_mfma_f32_16x16x32_bf16(qf[kc], kf, s[nt], 0, 0, 0);
      }
    }
    if (diag){
      int lrow = wave * 16 + quad * 4;
      #pragma unroll
      for (int nt = 0; nt < 4; ++nt)
        #pragma unroll
        for (int reg = 0; reg < 4; ++reg)
          if (nt * 16 + m16 > lrow + reg) s[nt][reg] = -1e30f;
    }
    #pragma unroll
    for (int reg = 0; reg < 4; ++reg){
      float rm = fmaxf(fmaxf(s[0][reg], s[1][reg]), fmaxf(s[2][reg], s[3][reg]));
      rm = fmaxf(rm, __shfl_xor(rm, 1));
      rm = fmaxf(rm, __shfl_xor(rm, 2));
      rm = fmaxf(rm, __shfl_xor(rm, 4));
      rm = fmaxf(rm, __shfl_xor(rm, 8));
      float mold = mst[reg];
      float mnew = fmaxf(mold, rm);
      float alpha = exp2f(mold - mnew);
      float rs = 0.f;
      #pragma unroll
      for (int nt = 0; nt < 4; ++nt){
        float p = exp2f(s[nt][reg] - mnew);
        s[nt][reg] = p;
        rs += p;
      }
      rs += __shfl_xor(rs, 1);
      rs += __shfl_xor(rs, 2);
      rs += __shfl_xor(rs, 4);
      rs += __shfl_xor(rs, 8);
      lst[reg] = lst[reg] * alpha + rs;
      mst[reg] = mnew;
      #pragma unroll
      for (int dt = 0; dt < 8; ++dt) oacc[dt][reg] *= alpha;
    }
    // P -> per-wave LDS (bf16, swizzled); same-wave DS ops are in-order
    #pragma unroll
    for (int nt = 0; nt < 4; ++nt)
      #pragma unroll
      for (int reg = 0; reg < 4; ++reg){
        int r   = quad * 4 + reg;
        int col = nt * 16 + m16;
        Pw[(r * 8 + ((col >> 3) ^ (r & 7))) * 8 + (col & 7)] = f2bf(s[nt][reg]);
      }
    #pragma unroll
    for (int kc = 0; kc < 2; ++kc){
      bf16x8 pf = *reinterpret_cast<const bf16x8*>(&Pw[(m16 * 8 + ((quad + 4 * kc) ^ (m16 & 7))) * 8]);
      #pragma unroll
      for (int dt = 0; dt < 8; ++dt){
        int r = dt * 16 + m16;
        bf16x8 vf = *reinterpret_cast<const bf16x8*>(&Vs[(r * 8 + ((quad + 4 * kc) ^ (r & 7))) * 8]);
        oacc[dt] = __builtin_amdgcn_mfma_f32_16x16x32_bf16(pf, vf, oacc[dt], 0, 0, 0);
      }
    }
  };

  stageKV(0, Ks0, Vs0);
  for (int base = 0; base < nkt; base += 2){
    __syncthreads();                              // drains loads(base)
    if (base + 1 < nkt) stageKV(base + 1, Ks1, Vs1);
    process(qf2, m2, l2, o2, Ks0, Vs0, base == nkt - 1);
    if (base <= g) process(qf1, m1, l1, o1, Ks0, Vs0, base == g);
    if (base + 1 >= nkt) break;
    __syncthreads();                              // drains loads(base+1)
    if (base + 2 < nkt) stageKV(base + 2, Ks0, Vs0);
    process(qf2, m2, l2, o2, Ks1, Vs1, base + 1 == nkt - 1);
    if (base + 1 <= g) process(qf1, m1, l1, o1, Ks1, Vs1, base + 1 == g);
  }

  const int b = bh >> 4, h = bh & 15;
  auto epi = [&](int qt, f32x4& lst, f32x4 (&oacc)[8]){
    #pragma unroll
    for (int reg = 0; reg < 4; ++reg){
      int t = qt * 64 + wave * 16 + quad * 4 + reg;
      float inv = 1.0f / lst[reg];
      size_t ob = ((size_t)b * 2048 + t) * 2048 + (size_t)h * 128;
      #pragma unroll
      for (int dt = 0; dt < 8; ++dt)
        AO[ob + dt * 16 + m16] = f2bf(oacc[dt][reg] * inv);
    }
  };
  epi(qt1, l1, o1);
  epi(qt2, l2, o2);
}

// ---------------------------------------------------------------- launch
extern "C" void kernel_launch(void* const* d_in, const int* in_sizes, int n_in,
                              void* d_out, int out_size, void* d_ws, size_t ws_size,
                              hipStream_t stream){
  const float* hs = (const float*)d_in[0];
  const float* qw = (const float*)d_in[2];
  const float* kw = (const float*)d_in[3];
  const float* vw = (const float*)d_in[4];
  const float* ow = (const float*)d_in[5];

  char* ws = (char*)d_ws;
  const size_t MB = 1ull << 20;
  unsigned short* hsb = (unsigned short*)(ws);
  unsigned short* qwb = (unsigned short*)(ws + 16 * MB);
  unsigned short* kwb = (unsigned short*)(ws + 24 * MB);
  unsigned short* vwb = (unsigned short*)(ws + 32 * MB);
  unsigned short* owb = (unsigned short*)(ws + 40 * MB);
  unsigned short* Qb  = (unsigned short*)(ws + 48 * MB);  // (B,H,T,D), pre-scaled by QSCALE
  unsigned short* Kb  = (unsigned short*)(ws + 64 * MB);  // (B,H,T,D)
  unsigned short* Vtb = (unsigned short*)(ws + 80 * MB);  // (B,H,D,T)
  unsigned short* AOb = (unsigned short*)(ws + 96 * MB);  // (B,T,HID)

  cvt_all_kernel<<<24576, 256, 0, stream>>>(hs, qw, kw, vw, ow, hsb, qwb, kwb, vwb, owb);

  dim3 g(16, 32);
  gemm_bt_kernel<0><<<g, 256, 0, stream>>>(hsb, qwb, Qb,  4096, 2048, 2048);
  gemm_bt_kernel<0><<<g, 256, 0, stream>>>(hsb, kwb, Kb,  4096, 2048, 2048);
  gemm_bt_kernel<1><<<g, 256, 0, stream>>>(hsb, vwb, Vtb, 4096, 2048, 2048);

  rope_kernel<<<32768, 256, 0, stream>>>(Qb, Kb);
  cam_kernel<<<32, 256, 0, stream>>>(Qb, Kb, Vtb);
  flash_kernel<<<dim3(16, 32), 256, 0, stream>>>(Qb, Kb, Vtb, AOb);

  gemm_bt_kernel<2><<<g, 256, 0, stream>>>(AOb, owb, d_out, 4096, 2048, 2048);
}

// Round 3
// 461.223 us; speedup vs baseline: 1.7547x; 1.7547x over previous
//
#include <hip/hip_runtime.h>
#include <cstdint>
#include <cstddef>

// B=2, T=2048, HID=2048, H=16, D=128; recent window m=512, ws=1536, evict=1535.

#define DEVINL __device__ __forceinline__

typedef float  f32x4  __attribute__((ext_vector_type(4)));
typedef __bf16 bf16x8 __attribute__((ext_vector_type(8)));

DEVINL float bf2f(unsigned short u){
  unsigned int x = ((unsigned int)u) << 16;
  return __builtin_bit_cast(float, x);
}
DEVINL unsigned short f2bf(float f){
  unsigned int u = __builtin_bit_cast(unsigned int, f);
  u = (u + 0x7fffu + ((u >> 16) & 1u)) >> 16;   // RNE
  return (unsigned short)u;
}

DEVINL void load_lds16(const void* g, void* l){
  __builtin_amdgcn_global_load_lds(
      (const __attribute__((address_space(1))) void*)g,
      (__attribute__((address_space(3))) void*)l, 16, 0, 0);
}

// Q pre-scale: log2(e)/sqrt(128) folded into RoPE'd Q so flash softmax is pure exp2.
#define QSCALE 0.127517432f

// ---------------------------------------------------------------- convert (all 5 tensors, one launch)
__global__ void cvt_all_kernel(const float* __restrict__ hs, const float* __restrict__ qw,
                               const float* __restrict__ kw, const float* __restrict__ vw,
                               const float* __restrict__ ow,
                               unsigned short* __restrict__ hsb, unsigned short* __restrict__ qwb,
                               unsigned short* __restrict__ kwb, unsigned short* __restrict__ vwb,
                               unsigned short* __restrict__ owb){
  int i = blockIdx.x * 256 + threadIdx.x;     // 6291456 float4 groups total
  const float* s; unsigned short* d; int off;
  if (i < 2097152){ s = hs; d = hsb; off = i; }
  else {
    int j = i - 2097152; int w = j >> 20; off = j & 1048575;
    s = (w == 0) ? qw : (w == 1) ? kw : (w == 2) ? vw : ow;
    d = (w == 0) ? qwb : (w == 1) ? kwb : (w == 2) ? vwb : owb;
  }
  float4 v = reinterpret_cast<const float4*>(s)[off];
  uint2 o;
  o.x = (unsigned)f2bf(v.x) | ((unsigned)f2bf(v.y) << 16);
  o.y = (unsigned)f2bf(v.z) | ((unsigned)f2bf(v.w) << 16);
  reinterpret_cast<uint2*>(d)[off] = o;
}

// ---------------------------------------------------------------- GEMM C = A @ B^T
// MODE 0: bf16 store scattered to (B,H,T,D)   [Q,K proj]
// MODE 1: bf16 store scattered to (B,H,D,T)   [V proj, pre-transposed]
// MODE 2: fp32 store row-major (M,N)          [output proj]
template<int MODE>
__global__ __launch_bounds__(256, 2)
void gemm_bt_kernel(const unsigned short* __restrict__ A,
                    const unsigned short* __restrict__ B,
                    void* __restrict__ out, int M, int N, int K){
  __shared__ unsigned short As[128 * 64];
  __shared__ unsigned short Bs[128 * 64];
  const int tid = threadIdx.x, wave = tid >> 6, lane = tid & 63;
  const int m16 = lane & 15, quad = lane >> 4;
  const int m0 = blockIdx.y * 128, n0 = blockIdx.x * 128;
  const int wm = wave >> 1, wn = wave & 1;

  f32x4 acc[4][4] = {};

  for (int k0 = 0; k0 < K; k0 += 64){
    __syncthreads();
    #pragma unroll
    for (int i = 0; i < 4; ++i){
      int r  = wave * 32 + i * 8 + (lane >> 3);
      int c8 = (lane & 7) ^ (r & 7);
      load_lds16(A + (size_t)(m0 + r) * K + k0 + c8 * 8, &As[(wave * 32 + i * 8) * 64]);
      load_lds16(B + (size_t)(n0 + r) * K + k0 + c8 * 8, &Bs[(wave * 32 + i * 8) * 64]);
    }
    __syncthreads();
    #pragma unroll
    for (int kc = 0; kc < 2; ++kc){
      bf16x8 af[4], bfr[4];
      #pragma unroll
      for (int mt = 0; mt < 4; ++mt){
        int r = wm * 64 + mt * 16 + m16;
        af[mt] = *reinterpret_cast<const bf16x8*>(&As[(r * 8 + ((quad + 4 * kc) ^ (r & 7))) * 8]);
      }
      #pragma unroll
      for (int nt = 0; nt < 4; ++nt){
        int r = wn * 64 + nt * 16 + m16;
        bfr[nt] = *reinterpret_cast<const bf16x8*>(&Bs[(r * 8 + ((quad + 4 * kc) ^ (r & 7))) * 8]);
      }
      #pragma unroll
      for (int mt = 0; mt < 4; ++mt)
        #pragma unroll
        for (int nt = 0; nt < 4; ++nt)
          acc[mt][nt] = __builtin_amdgcn_mfma_f32_16x16x32_bf16(af[mt], bfr[nt], acc[mt][nt], 0, 0, 0);
    }
  }

  #pragma unroll
  for (int mt = 0; mt < 4; ++mt){
    #pragma unroll
    for (int nt = 0; nt < 4; ++nt){
      #pragma unroll
      for (int reg = 0; reg < 4; ++reg){
        int m = m0 + wm * 64 + mt * 16 + quad * 4 + reg;
        int n = n0 + wn * 64 + nt * 16 + m16;
        float v = acc[mt][nt][reg];
        if constexpr (MODE == 0){
          ((unsigned short*)out)[((((size_t)(m >> 11)) * 16 + (n >> 7)) * 2048 + (m & 2047)) * 128 + (n & 127)] = f2bf(v);
        } else if constexpr (MODE == 1){
          ((unsigned short*)out)[((((size_t)(m >> 11)) * 16 + (n >> 7)) * 128 + (n & 127)) * 2048 + (m & 2047)] = f2bf(v);
        } else {
          ((float*)out)[(size_t)m * N + n] = v;
        }
      }
    }
  }
}

// ---------------------------------------------------------------- RoPE (in-place, Q then K; Q gets QSCALE)
__global__ void rope_kernel(unsigned short* __restrict__ Q, unsigned short* __restrict__ K){
  int gid = blockIdx.x * 256 + threadIdx.x;     // 2^23 threads
  int d2 = gid & 63;
  int t  = (gid >> 6) & 2047;
  int bh = (gid >> 17) & 31;
  int isK = gid >> 22;
  unsigned short* P = isK ? K : Q;
  float sc = isK ? 1.0f : QSCALE;
  size_t base = ((size_t)bh * 2048 + t) * 128;
  float x1 = bf2f(P[base + d2]);
  float x2 = bf2f(P[base + d2 + 64]);
  float inv = expf(-(float)d2 * 0.14391156606007266f);  // ln(10000)/64
  float fr = (float)t * inv;
  float sn, cs;
  sincosf(fr, &sn, &cs);
  P[base + d2]      = f2bf((x1 * cs - x2 * sn) * sc);
  P[base + d2 + 64] = f2bf((x2 * cs + x1 * sn) * sc);
}

// ---------------------------------------------------------------- CAM mask
DEVINL unsigned int rotl32(unsigned int x, int r){ return (x << r) | (x >> (32 - r)); }

__device__ float threefry_u01(int i){
  unsigned int c0 = (i < 16) ? (unsigned)i : (unsigned)(i - 16);
  unsigned int c1 = (i < 16) ? (unsigned)(i + 16) : (unsigned)i;
  bool hi = (i >= 16);
  unsigned int k0 = 0u, k1 = 42u, k2 = 0x1BD11BDAu ^ k0 ^ k1;
  unsigned int ks[3] = {k0, k1, k2};
  unsigned int x0 = c0 + k0, x1 = c1 + k1;
  const int R0[4] = {13, 15, 26, 6}, R1[4] = {17, 29, 16, 24};
  #pragma unroll
  for (int r = 0; r < 5; ++r){
    const int* RR = (r & 1) ? R1 : R0;
    #pragma unroll
    for (int j = 0; j < 4; ++j){ x0 += x1; x1 = rotl32(x1, RR[j]); x1 ^= x0; }
    x0 += ks[(r + 1) % 3];
    x1 += ks[(r + 2) % 3] + (unsigned)(r + 1);
  }
  unsigned int bits = hi ? x1 : x0;
  return __builtin_bit_cast(float, (bits >> 9) | 0x3f800000u) - 1.0f;
}

DEVINL float wred_max(float v){
  #pragma unroll
  for (int m = 1; m < 64; m <<= 1) v = fmaxf(v, __shfl_xor(v, m));
  return v;
}
DEVINL float wred_sum(float v){
  #pragma unroll
  for (int m = 1; m < 64; m <<= 1) v += __shfl_xor(v, m);
  return v;
}

__global__ __launch_bounds__(256)
void cam_kernel(const unsigned short* __restrict__ Q,
                const unsigned short* __restrict__ K,
                unsigned short* __restrict__ Vt){
  const int bh = blockIdx.x, tid = threadIdx.x;
  __shared__ float qv[128];
  __shared__ float redm[4], reds[4], redw[4];
  __shared__ float e1535s;
  __shared__ float bc0;
  if (tid < 128) qv[tid] = bf2f(Q[((size_t)bh * 2048 + 2047) * 128 + tid]);
  __syncthreads();

  float sc[8];
  float smax = -1e30f;
  #pragma unroll
  for (int j = 0; j < 8; ++j){
    int k = tid + j * 256;
    const uint4* kr4 = reinterpret_cast<const uint4*>(K + ((size_t)bh * 2048 + k) * 128);
    float acc = 0.f;
    #pragma unroll
    for (int c = 0; c < 16; ++c){
      uint4 pk = kr4[c];
      acc += qv[c * 8 + 0] * bf2f((unsigned short)(pk.x & 0xffff));
      acc += qv[c * 8 + 1] * bf2f((unsigned short)(pk.x >> 16));
      acc += qv[c * 8 + 2] * bf2f((unsigned short)(pk.y & 0xffff));
      acc += qv[c * 8 + 3] * bf2f((unsigned short)(pk.y >> 16));
      acc += qv[c * 8 + 4] * bf2f((unsigned short)(pk.z & 0xffff));
      acc += qv[c * 8 + 5] * bf2f((unsigned short)(pk.z >> 16));
      acc += qv[c * 8 + 6] * bf2f((unsigned short)(pk.w & 0xffff));
      acc += qv[c * 8 + 7] * bf2f((unsigned short)(pk.w >> 16));
    }
    sc[j] = acc;                                 // Q already carries scale*log2e
    smax = fmaxf(smax, sc[j]);
  }
  int wave = tid >> 6, lane = tid & 63;
  float wm = wred_max(smax);
  if (lane == 0) redm[wave] = wm;
  __syncthreads();
  float M = fmaxf(fmaxf(redm[0], redm[1]), fmaxf(redm[2], redm[3]));
  float tsum = 0.f, wsum = 0.f;
  #pragma unroll
  for (int j = 0; j < 8; ++j){
    int k = tid + j * 256;
    float e = exp2f(sc[j] - M);                  // 2^(s*log2e) == e^s
    if (k == 1535) e1535s = e;
    tsum += e;
    if (k >= 1536) wsum += e;
  }
  tsum = wred_sum(tsum); wsum = wred_sum(wsum);
  if (lane == 0){ reds[wave] = tsum; redw[wave] = wsum; }
  __syncthreads();
  if (tid == 0){
    float sum = reds[0] + reds[1] + reds[2] + reds[3];
    float wsm = redw[0] + redw[1] + redw[2] + redw[3];
    float abar = e1535s / sum;
    float avg  = fmaxf(wsm / (512.f * sum), 1e-6f);
    float pr   = abar / avg;
    pr = fminf(fmaxf(pr, 0.f), 1.f);
    float u = threefry_u01(bh);
    bc0 = (u < pr) ? (1.f / 512.f) : 0.f;
  }
  __syncthreads();
  float ves = bc0;
  if (ves != 0.f){
    for (int idx = tid; idx < 128 * 64; idx += 256){
      int d = idx >> 6, c = idx & 63;
      unsigned short* row = Vt + ((size_t)bh * 128 + d) * 2048;
      float ve = bf2f(row[1535]) * ves;
      uint4* p = reinterpret_cast<uint4*>(row + 1536) + c;
      uint4 pk = *p;
      unsigned short h0 = f2bf(bf2f((unsigned short)(pk.x & 0xffff)) + ve);
      unsigned short h1 = f2bf(bf2f((unsigned short)(pk.x >> 16)) + ve);
      unsigned short h2 = f2bf(bf2f((unsigned short)(pk.y & 0xffff)) + ve);
      unsigned short h3 = f2bf(bf2f((unsigned short)(pk.y >> 16)) + ve);
      unsigned short h4 = f2bf(bf2f((unsigned short)(pk.z & 0xffff)) + ve);
      unsigned short h5 = f2bf(bf2f((unsigned short)(pk.z >> 16)) + ve);
      unsigned short h6 = f2bf(bf2f((unsigned short)(pk.w & 0xffff)) + ve);
      unsigned short h7 = f2bf(bf2f((unsigned short)(pk.w >> 16)) + ve);
      pk.x = (unsigned)h0 | ((unsigned)h1 << 16);
      pk.y = (unsigned)h2 | ((unsigned)h3 << 16);
      pk.z = (unsigned)h4 | ((unsigned)h5 << 16);
      pk.w = (unsigned)h6 | ((unsigned)h7 << 16);
      *p = pk;
    }
  }
}

// ---------------------------------------------------------------- flash attention v3
// Balanced SEQUENTIAL pairing: block g runs q-tile g (k-tiles 0..g), then q-tile 31-g
// (k-tiles 0..31-g) — 33 k-iters per block, one accumulator context live at a time.
// Double-buffered K/V LDS; P overlays each wave's own (dead) Q rows.
__global__ __launch_bounds__(256, 2)
void flash_kernel(const unsigned short* __restrict__ Q,
                  const unsigned short* __restrict__ K,
                  const unsigned short* __restrict__ Vt,
                  unsigned short* __restrict__ AO){
  __shared__ unsigned short Qs[64 * 128];       // 16KB; per-wave P overlays own 16 rows
  __shared__ unsigned short Ks[2][64 * 128];    // 2 x 16KB
  __shared__ unsigned short Vs[2][128 * 64];    // 2 x 16KB  -> 80KB total, 2 blocks/CU
  const int g = blockIdx.x, bh = blockIdx.y;
  const int tid = threadIdx.x, wave = tid >> 6, lane = tid & 63;
  const int m16 = lane & 15, quad = lane >> 4;
  unsigned short* Pw = Qs + wave * 2048;        // wave's own 16x128-short span
  const int b = bh >> 4, h = bh & 15;

  #pragma unroll 1
  for (int phase = 0; phase < 2; ++phase){
    const int qt = phase ? (31 - g) : g;        // 64-row q-tile id
    const int nk = qt + 1;                      // causal k-tile count

    // ---- stage Q tile (each wave writes only its own 16 rows == its P region)
    {
      size_t qb = ((size_t)bh * 2048 + (size_t)qt * 64) * 128;
      #pragma unroll
      for (int i = 0; i < 4; ++i){
        int r   = wave * 16 + i * 4 + (lane >> 4);
        int c16 = (lane & 15) ^ (r & 15);
        load_lds16(Q + qb + (size_t)r * 128 + c16 * 8, &Qs[(wave * 16 + i * 4) * 128]);
      }
    }
    __syncthreads();                            // drains Q loads; fences prior phase
    bf16x8 qf[4];
    {
      int r = wave * 16 + m16;
      #pragma unroll
      for (int kc = 0; kc < 4; ++kc)
        qf[kc] = *reinterpret_cast<const bf16x8*>(&Qs[(r * 16 + ((quad + 4 * kc) ^ (r & 15))) * 8]);
    }

    f32x4 oacc[8] = {};
    f32x4 mst = {-1e30f, -1e30f, -1e30f, -1e30f};
    f32x4 lst = {};

    auto stageKV = [&](int kt, int buf){
      size_t kb = ((size_t)bh * 2048 + (size_t)kt * 64) * 128;
      #pragma unroll
      for (int i = 0; i < 4; ++i){
        int r   = wave * 16 + i * 4 + (lane >> 4);
        int c16 = (lane & 15) ^ (r & 15);
        load_lds16(K + kb + (size_t)r * 128 + c16 * 8, &Ks[buf][(wave * 16 + i * 4) * 128]);
      }
      size_t vb = (size_t)bh * 128 * 2048 + (size_t)kt * 64;
      #pragma unroll
      for (int i = 0; i < 4; ++i){
        int r  = wave * 32 + i * 8 + (lane >> 3);
        int c8 = (lane & 7) ^ (r & 7);
        load_lds16(Vt + vb + (size_t)r * 2048 + c8 * 8, &Vs[buf][(wave * 32 + i * 8) * 64]);
      }
    };

    stageKV(0, 0);
    #pragma unroll 1
    for (int t = 0; t < nk; ++t){
      const int buf = t & 1;
      __syncthreads();                          // drains stage(t); publishes tile t
      if (t + 1 < nk) stageKV(t + 1, buf ^ 1);  // prefetch overlaps compute

      // ---- S = Q K^T  (wave: 16 q-rows x 64 keys)
      f32x4 s[4] = {};
      #pragma unroll
      for (int kc = 0; kc < 4; ++kc){
        #pragma unroll
        for (int nt = 0; nt < 4; ++nt){
          int r = nt * 16 + m16;
          bf16x8 kf = *reinterpret_cast<const bf16x8*>(&Ks[buf][(r * 16 + ((quad + 4 * kc) ^ (r & 15))) * 8]);
          s[nt] = __builtin_amdgcn_mfma_f32_16x16x32_bf16(qf[kc], kf, s[nt], 0, 0, 0);
        }
      }
      if (t == nk - 1){                         // diagonal tile mask
        int lrow = wave * 16 + quad * 4;
        #pragma unroll
        for (int nt = 0; nt < 4; ++nt)
          #pragma unroll
          for (int reg = 0; reg < 4; ++reg)
            if (nt * 16 + m16 > lrow + reg) s[nt][reg] = -1e30f;
      }
      // ---- online softmax (row = quad*4+reg)
      #pragma unroll
      for (int reg = 0; reg < 4; ++reg){
        float rm = fmaxf(fmaxf(s[0][reg], s[1][reg]), fmaxf(s[2][reg], s[3][reg]));
        rm = fmaxf(rm, __shfl_xor(rm, 1));
        rm = fmaxf(rm, __shfl_xor(rm, 2));
        rm = fmaxf(rm, __shfl_xor(rm, 4));
        rm = fmaxf(rm, __shfl_xor(rm, 8));
        float mold = mst[reg];
        float mnew = fmaxf(mold, rm);
        float alpha = exp2f(mold - mnew);
        float rs = 0.f;
        #pragma unroll
        for (int nt = 0; nt < 4; ++nt){
          float p = exp2f(s[nt][reg] - mnew);
          s[nt][reg] = p;
          rs += p;
        }
        rs += __shfl_xor(rs, 1);
        rs += __shfl_xor(rs, 2);
        rs += __shfl_xor(rs, 4);
        rs += __shfl_xor(rs, 8);
        lst[reg] = lst[reg] * alpha + rs;
        mst[reg] = mnew;
        #pragma unroll
        for (int dt = 0; dt < 8; ++dt) oacc[dt][reg] *= alpha;
      }
      // ---- P -> wave-private LDS (same-wave DS ordering)
      #pragma unroll
      for (int nt = 0; nt < 4; ++nt)
        #pragma unroll
        for (int reg = 0; reg < 4; ++reg){
          int r   = quad * 4 + reg;
          int col = nt * 16 + m16;
          Pw[(r * 8 + ((col >> 3) ^ (r & 7))) * 8 + (col & 7)] = f2bf(s[nt][reg]);
        }
      // ---- O += P @ V
      #pragma unroll
      for (int kc = 0; kc < 2; ++kc){
        bf16x8 pf = *reinterpret_cast<const bf16x8*>(&Pw[(m16 * 8 + ((quad + 4 * kc) ^ (m16 & 7))) * 8]);
        #pragma unroll
        for (int dt = 0; dt < 8; ++dt){
          int r = dt * 16 + m16;
          bf16x8 vf = *reinterpret_cast<const bf16x8*>(&Vs[buf][(r * 8 + ((quad + 4 * kc) ^ (r & 7))) * 8]);
          oacc[dt] = __builtin_amdgcn_mfma_f32_16x16x32_bf16(pf, vf, oacc[dt], 0, 0, 0);
        }
      }
    }

    // ---- epilogue
    #pragma unroll
    for (int reg = 0; reg < 4; ++reg){
      int tq = qt * 64 + wave * 16 + quad * 4 + reg;
      float inv = 1.0f / lst[reg];
      size_t ob = ((size_t)b * 2048 + tq) * 2048 + (size_t)h * 128;
      #pragma unroll
      for (int dt = 0; dt < 8; ++dt)
        AO[ob + dt * 16 + m16] = f2bf(oacc[dt][reg] * inv);
    }
  }
}

// ---------------------------------------------------------------- launch
extern "C" void kernel_launch(void* const* d_in, const int* in_sizes, int n_in,
                              void* d_out, int out_size, void* d_ws, size_t ws_size,
                              hipStream_t stream){
  const float* hs = (const float*)d_in[0];
  const float* qw = (const float*)d_in[2];
  const float* kw = (const float*)d_in[3];
  const float* vw = (const float*)d_in[4];
  const float* ow = (const float*)d_in[5];

  char* ws = (char*)d_ws;
  const size_t MB = 1ull << 20;
  unsigned short* hsb = (unsigned short*)(ws);
  unsigned short* qwb = (unsigned short*)(ws + 16 * MB);
  unsigned short* kwb = (unsigned short*)(ws + 24 * MB);
  unsigned short* vwb = (unsigned short*)(ws + 32 * MB);
  unsigned short* owb = (unsigned short*)(ws + 40 * MB);
  unsigned short* Qb  = (unsigned short*)(ws + 48 * MB);  // (B,H,T,D), pre-scaled by QSCALE
  unsigned short* Kb  = (unsigned short*)(ws + 64 * MB);  // (B,H,T,D)
  unsigned short* Vtb = (unsigned short*)(ws + 80 * MB);  // (B,H,D,T)
  unsigned short* AOb = (unsigned short*)(ws + 96 * MB);  // (B,T,HID)

  cvt_all_kernel<<<24576, 256, 0, stream>>>(hs, qw, kw, vw, ow, hsb, qwb, kwb, vwb, owb);

  dim3 g(16, 32);
  gemm_bt_kernel<0><<<g, 256, 0, stream>>>(hsb, qwb, Qb,  4096, 2048, 2048);
  gemm_bt_kernel<0><<<g, 256, 0, stream>>>(hsb, kwb, Kb,  4096, 2048, 2048);
  gemm_bt_kernel<1><<<g, 256, 0, stream>>>(hsb, vwb, Vtb, 4096, 2048, 2048);

  rope_kernel<<<32768, 256, 0, stream>>>(Qb, Kb);
  cam_kernel<<<32, 256, 0, stream>>>(Qb, Kb, Vtb);
  flash_kernel<<<dim3(16, 32), 256, 0, stream>>>(Qb, Kb, Vtb, AOb);

  gemm_bt_kernel<2><<<g, 256, 0, stream>>>(AOb, owb, d_out, 4096, 2048, 2048);
}

// Round 5
// 458.755 us; speedup vs baseline: 1.7641x; 1.0054x over previous
//
#include <hip/hip_runtime.h>
#include <cstdint>
#include <cstddef>

// B=2, T=2048, HID=2048, H=16, D=128; recent window m=512, ws=1536, evict=1535.

#define DEVINL __device__ __forceinline__

typedef float  f32x4  __attribute__((ext_vector_type(4)));
typedef __bf16 bf16x8 __attribute__((ext_vector_type(8)));

DEVINL float bf2f(unsigned short u){
  unsigned int x = ((unsigned int)u) << 16;
  return __builtin_bit_cast(float, x);
}
DEVINL void store_bf(unsigned short* p, float f){
  *(__bf16*)p = (__bf16)f;                      // native cvt (RNE)
}

DEVINL void load_lds16(const void* g, void* l){
  __builtin_amdgcn_global_load_lds(
      (const __attribute__((address_space(1))) void*)g,
      (__attribute__((address_space(3))) void*)l, 16, 0, 0);
}

// Q pre-scale: log2(e)/sqrt(128) folded into RoPE'd Q so flash softmax is pure exp2.
#define QSCALE 0.127517432f

// ---------------------------------------------------------------- convert (all 5 tensors, one launch)
__global__ void cvt_all_kernel(const float* __restrict__ hs, const float* __restrict__ qw,
                               const float* __restrict__ kw, const float* __restrict__ vw,
                               const float* __restrict__ ow,
                               unsigned short* __restrict__ hsb, unsigned short* __restrict__ qwb,
                               unsigned short* __restrict__ kwb, unsigned short* __restrict__ vwb,
                               unsigned short* __restrict__ owb){
  int i = blockIdx.x * 256 + threadIdx.x;     // 6291456 float4 groups total
  const float* s; unsigned short* d; int off;
  if (i < 2097152){ s = hs; d = hsb; off = i; }
  else {
    int j = i - 2097152; int w = j >> 20; off = j & 1048575;
    s = (w == 0) ? qw : (w == 1) ? kw : (w == 2) ? vw : ow;
    d = (w == 0) ? qwb : (w == 1) ? kwb : (w == 2) ? vwb : owb;
  }
  float4 v = reinterpret_cast<const float4*>(s)[off];
  unsigned short o[4];
  store_bf(&o[0], v.x); store_bf(&o[1], v.y); store_bf(&o[2], v.z); store_bf(&o[3], v.w);
  reinterpret_cast<uint2*>(d)[off] = *reinterpret_cast<uint2*>(o);
}

// ---------------------------------------------------------------- GEMM C = A @ B^T
// MODE 0: fused QKV — N=6144, n<2048 -> Q (B,H,T,D); <4096 -> K (B,H,T,D); else V^T (B,H,D,T)
// MODE 2: fp32 store row-major (M,N)          [output proj]
template<int MODE>
__global__ __launch_bounds__(256, 3)
void gemm_bt_kernel(const unsigned short* __restrict__ A,
                    const unsigned short* __restrict__ B,
                    unsigned short* __restrict__ Qo, unsigned short* __restrict__ Ko,
                    unsigned short* __restrict__ Vo, float* __restrict__ Co,
                    int M, int N, int K){
  __shared__ unsigned short As[128 * 64];
  __shared__ unsigned short Bs[128 * 64];
  const int tid = threadIdx.x, wave = tid >> 6, lane = tid & 63;
  const int m16 = lane & 15, quad = lane >> 4;
  const int m0 = blockIdx.y * 128, n0 = blockIdx.x * 128;
  const int wm = wave >> 1, wn = wave & 1;

  f32x4 acc[4][4] = {};

  for (int k0 = 0; k0 < K; k0 += 64){
    __syncthreads();
    #pragma unroll
    for (int i = 0; i < 4; ++i){
      int r  = wave * 32 + i * 8 + (lane >> 3);
      int c8 = (lane & 7) ^ (r & 7);
      load_lds16(A + (size_t)(m0 + r) * K + k0 + c8 * 8, &As[(wave * 32 + i * 8) * 64]);
      load_lds16(B + (size_t)(n0 + r) * K + k0 + c8 * 8, &Bs[(wave * 32 + i * 8) * 64]);
    }
    __syncthreads();
    #pragma unroll
    for (int kc = 0; kc < 2; ++kc){
      bf16x8 af[4], bfr[4];
      #pragma unroll
      for (int mt = 0; mt < 4; ++mt){
        int r = wm * 64 + mt * 16 + m16;
        af[mt] = *reinterpret_cast<const bf16x8*>(&As[(r * 8 + ((quad + 4 * kc) ^ (r & 7))) * 8]);
      }
      #pragma unroll
      for (int nt = 0; nt < 4; ++nt){
        int r = wn * 64 + nt * 16 + m16;
        bfr[nt] = *reinterpret_cast<const bf16x8*>(&Bs[(r * 8 + ((quad + 4 * kc) ^ (r & 7))) * 8]);
      }
      #pragma unroll
      for (int mt = 0; mt < 4; ++mt)
        #pragma unroll
        for (int nt = 0; nt < 4; ++nt)
          acc[mt][nt] = __builtin_amdgcn_mfma_f32_16x16x32_bf16(af[mt], bfr[nt], acc[mt][nt], 0, 0, 0);
    }
  }

  #pragma unroll
  for (int mt = 0; mt < 4; ++mt){
    #pragma unroll
    for (int nt = 0; nt < 4; ++nt){
      #pragma unroll
      for (int reg = 0; reg < 4; ++reg){
        int m = m0 + wm * 64 + mt * 16 + quad * 4 + reg;
        int n = n0 + wn * 64 + nt * 16 + m16;
        float v = acc[mt][nt][reg];
        if constexpr (MODE == 0){
          int which = n >> 11;                  // uniform per block (n0 multiple of 128)
          int nn = n & 2047;
          int bq = m >> 11, t = m & 2047, hd = nn >> 7, dd = nn & 127;
          if (which == 0)
            store_bf(&Qo[((((size_t)bq) * 16 + hd) * 2048 + t) * 128 + dd], v);
          else if (which == 1)
            store_bf(&Ko[((((size_t)bq) * 16 + hd) * 2048 + t) * 128 + dd], v);
          else
            store_bf(&Vo[((((size_t)bq) * 16 + hd) * 128 + dd) * 2048 + t], v);
        } else {
          Co[(size_t)m * N + n] = v;
        }
      }
    }
  }
}

// ---------------------------------------------------------------- RoPE (in-place, Q then K; Q gets QSCALE)
__global__ void rope_kernel(unsigned short* __restrict__ Q, unsigned short* __restrict__ K){
  int gid = blockIdx.x * 256 + threadIdx.x;     // 2^23 threads
  int d2 = gid & 63;
  int t  = (gid >> 6) & 2047;
  int bh = (gid >> 17) & 31;
  int isK = gid >> 22;
  unsigned short* P = isK ? K : Q;
  float sc = isK ? 1.0f : QSCALE;
  size_t base = ((size_t)bh * 2048 + t) * 128;
  float x1 = bf2f(P[base + d2]);
  float x2 = bf2f(P[base + d2 + 64]);
  float inv = expf(-(float)d2 * 0.14391156606007266f);  // ln(10000)/64
  float fr = (float)t * inv;
  float sn, cs;
  sincosf(fr, &sn, &cs);
  store_bf(&P[base + d2],      (x1 * cs - x2 * sn) * sc);
  store_bf(&P[base + d2 + 64], (x2 * cs + x1 * sn) * sc);
}

// ---------------------------------------------------------------- CAM mask
DEVINL unsigned int rotl32(unsigned int x, int r){ return (x << r) | (x >> (32 - r)); }

__device__ float threefry_u01(int i){
  unsigned int c0 = (i < 16) ? (unsigned)i : (unsigned)(i - 16);
  unsigned int c1 = (i < 16) ? (unsigned)(i + 16) : (unsigned)i;
  bool hi = (i >= 16);
  unsigned int k0 = 0u, k1 = 42u, k2 = 0x1BD11BDAu ^ k0 ^ k1;
  unsigned int ks[3] = {k0, k1, k2};
  unsigned int x0 = c0 + k0, x1 = c1 + k1;
  const int R0[4] = {13, 15, 26, 6}, R1[4] = {17, 29, 16, 24};
  #pragma unroll
  for (int r = 0; r < 5; ++r){
    const int* RR = (r & 1) ? R1 : R0;
    #pragma unroll
    for (int j = 0; j < 4; ++j){ x0 += x1; x1 = rotl32(x1, RR[j]); x1 ^= x0; }
    x0 += ks[(r + 1) % 3];
    x1 += ks[(r + 2) % 3] + (unsigned)(r + 1);
  }
  unsigned int bits = hi ? x1 : x0;
  return __builtin_bit_cast(float, (bits >> 9) | 0x3f800000u) - 1.0f;
}

DEVINL float wred_max(float v){
  #pragma unroll
  for (int m = 1; m < 64; m <<= 1) v = fmaxf(v, __shfl_xor(v, m));
  return v;
}
DEVINL float wred_sum(float v){
  #pragma unroll
  for (int m = 1; m < 64; m <<= 1) v += __shfl_xor(v, m);
  return v;
}

__global__ __launch_bounds__(256)
void cam_kernel(const unsigned short* __restrict__ Q,
                const unsigned short* __restrict__ K,
                unsigned short* __restrict__ Vt){
  const int bh = blockIdx.x, tid = threadIdx.x;
  __shared__ float qv[128];
  __shared__ float redm[4], reds[4], redw[4];
  __shared__ float e1535s;
  __shared__ float bc0;
  if (tid < 128) qv[tid] = bf2f(Q[((size_t)bh * 2048 + 2047) * 128 + tid]);
  __syncthreads();

  float sc[8];
  float smax = -1e30f;
  #pragma unroll
  for (int j = 0; j < 8; ++j){
    int k = tid + j * 256;
    const uint4* kr4 = reinterpret_cast<const uint4*>(K + ((size_t)bh * 2048 + k) * 128);
    float acc = 0.f;
    #pragma unroll
    for (int c = 0; c < 16; ++c){
      uint4 pk = kr4[c];
      acc += qv[c * 8 + 0] * bf2f((unsigned short)(pk.x & 0xffff));
      acc += qv[c * 8 + 1] * bf2f((unsigned short)(pk.x >> 16));
      acc += qv[c * 8 + 2] * bf2f((unsigned short)(pk.y & 0xffff));
      acc += qv[c * 8 + 3] * bf2f((unsigned short)(pk.y >> 16));
      acc += qv[c * 8 + 4] * bf2f((unsigned short)(pk.z & 0xffff));
      acc += qv[c * 8 + 5] * bf2f((unsigned short)(pk.z >> 16));
      acc += qv[c * 8 + 6] * bf2f((unsigned short)(pk.w & 0xffff));
      acc += qv[c * 8 + 7] * bf2f((unsigned short)(pk.w >> 16));
    }
    sc[j] = acc;                                 // Q already carries scale*log2e
    smax = fmaxf(smax, sc[j]);
  }
  int wave = tid >> 6, lane = tid & 63;
  float wm = wred_max(smax);
  if (lane == 0) redm[wave] = wm;
  __syncthreads();
  float M = fmaxf(fmaxf(redm[0], redm[1]), fmaxf(redm[2], redm[3]));
  float tsum = 0.f, wsum = 0.f;
  #pragma unroll
  for (int j = 0; j < 8; ++j){
    int k = tid + j * 256;
    float e = exp2f(sc[j] - M);                  // 2^(s*log2e) == e^s
    if (k == 1535) e1535s = e;
    tsum += e;
    if (k >= 1536) wsum += e;
  }
  tsum = wred_sum(tsum); wsum = wred_sum(wsum);
  if (lane == 0){ reds[wave] = tsum; redw[wave] = wsum; }
  __syncthreads();
  if (tid == 0){
    float sum = reds[0] + reds[1] + reds[2] + reds[3];
    float wsm = redw[0] + redw[1] + redw[2] + redw[3];
    float abar = e1535s / sum;
    float avg  = fmaxf(wsm / (512.f * sum), 1e-6f);
    float pr   = abar / avg;
    pr = fminf(fmaxf(pr, 0.f), 1.f);
    float u = threefry_u01(bh);
    bc0 = (u < pr) ? (1.f / 512.f) : 0.f;
  }
  __syncthreads();
  float ves = bc0;
  if (ves != 0.f){
    for (int idx = tid; idx < 128 * 64; idx += 256){
      int d = idx >> 6, c = idx & 63;
      unsigned short* row = Vt + ((size_t)bh * 128 + d) * 2048;
      float ve = bf2f(row[1535]) * ves;
      uint4* p = reinterpret_cast<uint4*>(row + 1536) + c;
      uint4 pk = *p;
      unsigned short h[8];
      store_bf(&h[0], bf2f((unsigned short)(pk.x & 0xffff)) + ve);
      store_bf(&h[1], bf2f((unsigned short)(pk.x >> 16)) + ve);
      store_bf(&h[2], bf2f((unsigned short)(pk.y & 0xffff)) + ve);
      store_bf(&h[3], bf2f((unsigned short)(pk.y >> 16)) + ve);
      store_bf(&h[4], bf2f((unsigned short)(pk.z & 0xffff)) + ve);
      store_bf(&h[5], bf2f((unsigned short)(pk.z >> 16)) + ve);
      store_bf(&h[6], bf2f((unsigned short)(pk.w & 0xffff)) + ve);
      store_bf(&h[7], bf2f((unsigned short)(pk.w >> 16)) + ve);
      pk.x = (unsigned)h[0] | ((unsigned)h[1] << 16);
      pk.y = (unsigned)h[2] | ((unsigned)h[3] << 16);
      pk.z = (unsigned)h[4] | ((unsigned)h[5] << 16);
      pk.w = (unsigned)h[6] | ((unsigned)h[7] << 16);
      *p = pk;
    }
  }
}

// ---------------------------------------------------------------- flash attention v4
// Balanced sequential pairing (block g: q-tile g then 31-g). Double-buffered K/V LDS.
// l computed via extra MFMA against all-ones B fragment (no sum shuffles).
__global__ __launch_bounds__(256, 2)
void flash_kernel(const unsigned short* __restrict__ Q,
                  const unsigned short* __restrict__ K,
                  const unsigned short* __restrict__ Vt,
                  unsigned short* __restrict__ AO){
  __shared__ unsigned short Qs[64 * 128];       // 16KB; per-wave P overlays own 16 rows
  __shared__ unsigned short Ks[2][64 * 128];    // 2 x 16KB
  __shared__ unsigned short Vs[2][128 * 64];    // 2 x 16KB  -> 80KB total, 2 blocks/CU
  const int g = blockIdx.x, bh = blockIdx.y;
  const int tid = threadIdx.x, wave = tid >> 6, lane = tid & 63;
  const int m16 = lane & 15, quad = lane >> 4;
  unsigned short* Pw = Qs + wave * 2048;        // wave's own 16x128-short span
  const int b = bh >> 4, h = bh & 15;

  bf16x8 onesf;
  #pragma unroll
  for (int j = 0; j < 8; ++j) onesf[j] = (__bf16)1.0f;

  #pragma unroll 1
  for (int phase = 0; phase < 2; ++phase){
    const int qt = phase ? (31 - g) : g;        // 64-row q-tile id
    const int nk = qt + 1;                      // causal k-tile count

    {
      size_t qb = ((size_t)bh * 2048 + (size_t)qt * 64) * 128;
      #pragma unroll
      for (int i = 0; i < 4; ++i){
        int r   = wave * 16 + i * 4 + (lane >> 4);
        int c16 = (lane & 15) ^ (r & 15);
        load_lds16(Q + qb + (size_t)r * 128 + c16 * 8, &Qs[(wave * 16 + i * 4) * 128]);
      }
    }
    __syncthreads();                            // drains Q loads; fences prior phase
    bf16x8 qf[4];
    {
      int r = wave * 16 + m16;
      #pragma unroll
      for (int kc = 0; kc < 4; ++kc)
        qf[kc] = *reinterpret_cast<const bf16x8*>(&Qs[(r * 16 + ((quad + 4 * kc) ^ (r & 15))) * 8]);
    }

    f32x4 oacc[8] = {};
    f32x4 oaccL = {};                           // row-sum accumulator (all cols identical)
    f32x4 mst = {-1e30f, -1e30f, -1e30f, -1e30f};

    auto stageKV = [&](int kt, int buf){
      size_t kb = ((size_t)bh * 2048 + (size_t)kt * 64) * 128;
      #pragma unroll
      for (int i = 0; i < 4; ++i){
        int r   = wave * 16 + i * 4 + (lane >> 4);
        int c16 = (lane & 15) ^ (r & 15);
        load_lds16(K + kb + (size_t)r * 128 + c16 * 8, &Ks[buf][(wave * 16 + i * 4) * 128]);
      }
      size_t vb = (size_t)bh * 128 * 2048 + (size_t)kt * 64;
      #pragma unroll
      for (int i = 0; i < 4; ++i){
        int r  = wave * 32 + i * 8 + (lane >> 3);
        int c8 = (lane & 7) ^ (r & 7);
        load_lds16(Vt + vb + (size_t)r * 2048 + c8 * 8, &Vs[buf][(wave * 32 + i * 8) * 64]);
      }
    };

    stageKV(0, 0);
    #pragma unroll 1
    for (int t = 0; t < nk; ++t){
      const int buf = t & 1;
      __syncthreads();                          // drains stage(t); publishes tile t
      if (t + 1 < nk) stageKV(t + 1, buf ^ 1);  // prefetch overlaps compute

      // ---- S = Q K^T  (wave: 16 q-rows x 64 keys)
      f32x4 s[4] = {};
      #pragma unroll
      for (int kc = 0; kc < 4; ++kc){
        #pragma unroll
        for (int nt = 0; nt < 4; ++nt){
          int r = nt * 16 + m16;
          bf16x8 kf = *reinterpret_cast<const bf16x8*>(&Ks[buf][(r * 16 + ((quad + 4 * kc) ^ (r & 15))) * 8]);
          s[nt] = __builtin_amdgcn_mfma_f32_16x16x32_bf16(qf[kc], kf, s[nt], 0, 0, 0);
        }
      }
      if (t == nk - 1){                         // diagonal tile mask
        int lrow = wave * 16 + quad * 4;
        #pragma unroll
        for (int nt = 0; nt < 4; ++nt)
          #pragma unroll
          for (int reg = 0; reg < 4; ++reg)
            if (nt * 16 + m16 > lrow + reg) s[nt][reg] = -1e30f;
      }
      // ---- online softmax (row = quad*4+reg); l folded into MFMA below
      f32x4 av;
      #pragma unroll
      for (int reg = 0; reg < 4; ++reg){
        float rm = fmaxf(fmaxf(s[0][reg], s[1][reg]), fmaxf(s[2][reg], s[3][reg]));
        rm = fmaxf(rm, __shfl_xor(rm, 1));
        rm = fmaxf(rm, __shfl_xor(rm, 2));
        rm = fmaxf(rm, __shfl_xor(rm, 4));
        rm = fmaxf(rm, __shfl_xor(rm, 8));
        float mold = mst[reg];
        float mnew = fmaxf(mold, rm);
        av[reg] = exp2f(mold - mnew);
        mst[reg] = mnew;
        #pragma unroll
        for (int nt = 0; nt < 4; ++nt)
          s[nt][reg] = exp2f(s[nt][reg] - mnew);
      }
      oaccL *= av;
      #pragma unroll
      for (int dt = 0; dt < 8; ++dt) oacc[dt] *= av;

      // ---- P -> wave-private LDS (same-wave DS ordering)
      #pragma unroll
      for (int nt = 0; nt < 4; ++nt)
        #pragma unroll
        for (int reg = 0; reg < 4; ++reg){
          int r   = quad * 4 + reg;
          int col = nt * 16 + m16;
          store_bf(&Pw[(r * 8 + ((col >> 3) ^ (r & 7))) * 8 + (col & 7)], s[nt][reg]);
        }
      // ---- O += P @ V ; l += P @ 1
      #pragma unroll
      for (int kc = 0; kc < 2; ++kc){
        bf16x8 pf = *reinterpret_cast<const bf16x8*>(&Pw[(m16 * 8 + ((quad + 4 * kc) ^ (m16 & 7))) * 8]);
        oaccL = __builtin_amdgcn_mfma_f32_16x16x32_bf16(pf, onesf, oaccL, 0, 0, 0);
        #pragma unroll
        for (int dt = 0; dt < 8; ++dt){
          int r = dt * 16 + m16;
          bf16x8 vf = *reinterpret_cast<const bf16x8*>(&Vs[buf][(r * 8 + ((quad + 4 * kc) ^ (r & 7))) * 8]);
          oacc[dt] = __builtin_amdgcn_mfma_f32_16x16x32_bf16(pf, vf, oacc[dt], 0, 0, 0);
        }
      }
    }

    // ---- epilogue
    #pragma unroll
    for (int reg = 0; reg < 4; ++reg){
      int tq = qt * 64 + wave * 16 + quad * 4 + reg;
      float inv = 1.0f / oaccL[reg];
      size_t ob = ((size_t)b * 2048 + tq) * 2048 + (size_t)h * 128;
      #pragma unroll
      for (int dt = 0; dt < 8; ++dt)
        store_bf(&AO[ob + dt * 16 + m16], oacc[dt][reg] * inv);
    }
  }
}

// ---------------------------------------------------------------- launch
extern "C" void kernel_launch(void* const* d_in, const int* in_sizes, int n_in,
                              void* d_out, int out_size, void* d_ws, size_t ws_size,
                              hipStream_t stream){
  const float* hs = (const float*)d_in[0];
  const float* qw = (const float*)d_in[2];
  const float* kw = (const float*)d_in[3];
  const float* vw = (const float*)d_in[4];
  const float* ow = (const float*)d_in[5];

  char* ws = (char*)d_ws;
  const size_t MB = 1ull << 20;
  unsigned short* hsb = (unsigned short*)(ws);            // 16 MB
  unsigned short* qwb = (unsigned short*)(ws + 16 * MB);  // qwb/kwb/vwb contiguous: fused B (6144,2048)
  unsigned short* kwb = (unsigned short*)(ws + 24 * MB);
  unsigned short* vwb = (unsigned short*)(ws + 32 * MB);
  unsigned short* owb = (unsigned short*)(ws + 40 * MB);
  unsigned short* Qb  = (unsigned short*)(ws + 48 * MB);  // (B,H,T,D), pre-scaled by QSCALE
  unsigned short* Kb  = (unsigned short*)(ws + 64 * MB);  // (B,H,T,D)
  unsigned short* Vtb = (unsigned short*)(ws + 80 * MB);  // (B,H,D,T)
  unsigned short* AOb = (unsigned short*)(ws + 96 * MB);  // (B,T,HID)

  cvt_all_kernel<<<24576, 256, 0, stream>>>(hs, qw, kw, vw, ow, hsb, qwb, kwb, vwb, owb);

  gemm_bt_kernel<0><<<dim3(48, 32), 256, 0, stream>>>(hsb, qwb, Qb, Kb, Vtb, nullptr,
                                                      4096, 6144, 2048);

  rope_kernel<<<32768, 256, 0, stream>>>(Qb, Kb);
  cam_kernel<<<32, 256, 0, stream>>>(Qb, Kb, Vtb);
  flash_kernel<<<dim3(16, 32), 256, 0, stream>>>(Qb, Kb, Vtb, AOb);

  gemm_bt_kernel<2><<<dim3(16, 32), 256, 0, stream>>>(AOb, owb, nullptr, nullptr, nullptr,
                                                      (float*)d_out, 4096, 2048, 2048);
}